// Round 3
// baseline (308.001 us; speedup 1.0000x reference)
//
#include <hip/hip_runtime.h>
#include <stdint.h>

// LorentzLinear fused: y = x @ W^T + b ; time = sigmoid(y0)*e^scale + 1.1 ;
// out = [time, y_narrow * sqrt((time^2-1)/max(sum(y_narrow^2),1e-8))]
// M=65536, K=512, N=512.
// R2: 32x32x16 MFMA, BK=16, depth-3 LDS pipeline with counted vmcnt +
// raw s_barrier (no vmcnt(0) drain in main loop). [col][k] W-tile layout
// makes all fragment ds_read_b128 dense 1024B blocks -> conflict-free,
// linear (no swizzle) -> global_load_lds legal.

typedef short short8 __attribute__((ext_vector_type(8)));
typedef float f32x16 __attribute__((ext_vector_type(16)));
typedef unsigned short ushort4v __attribute__((ext_vector_type(4)));

#define THREADS 512
#define BM 64
#define WTILE 16384       // 512 cols x 16 k x 2B
#define XTILE 2048        // 64 rows x 16 k x 2B
#define PHASE (WTILE + XTILE)   // 18432; 3 phases = 55296 B -> 2 blocks/CU

__device__ __forceinline__ unsigned short f2bf(float f) {
  union { float f; uint32_t u; } v; v.f = f;
  uint32_t u = v.u;
  return (unsigned short)((u + 0x7FFFu + ((u >> 16) & 1u)) >> 16);  // RNE
}

__device__ __forceinline__ void gload_lds16(const void* g, void* l) {
  __builtin_amdgcn_global_load_lds(
      (const __attribute__((address_space(1))) void*)g,
      (__attribute__((address_space(3))) void*)l, 16, 0, 0);
}

// W fp32 -> bf16 once per launch (d_ws re-poisoned every run)
__global__ void wconv_kernel(const float* __restrict__ w,
                             unsigned short* __restrict__ wb) {
  const int i = (blockIdx.x * blockDim.x + threadIdx.x) * 4;
  float4 f = *(const float4*)(w + i);
  ushort4v h;
  h[0] = f2bf(f.x); h[1] = f2bf(f.y); h[2] = f2bf(f.z); h[3] = f2bf(f.w);
  *(ushort4v*)(wb + i) = h;
}

__global__ __launch_bounds__(THREADS, 4) void lorentz_kernel(
    const float* __restrict__ xg, const unsigned short* __restrict__ wb,
    const float* __restrict__ bg, const float* __restrict__ sg,
    float* __restrict__ out) {
  __shared__ __align__(16) char smem[3 * PHASE];
  const int t = threadIdx.x;
  const int lane = t & 63;
  const int wid = t >> 6;
  const int wm = wid >> 2;        // 0..1 : 32-row half
  const int wn = wid & 3;         // 0..3 : 128-col quarter
  const int l31 = lane & 31;
  const int h = lane >> 5;
  const int bm = blockIdx.x * BM;

  char* const P0 = smem;
  char* const P1 = smem + PHASE;
  char* const P2 = smem + 2 * PHASE;

  // W staging: thread t, iter i: dest byte i*8192 + t*16 -> col i*256+(t>>1),
  // k-half 8*(t&1). Source mirrors that (linear, no swizzle needed).
  const unsigned short* wsrc0 = wb + (t >> 1) * 512 + (t & 1) * 8;
  // x staging: row t>>3, 2 floats at k-offset (t&7)*2
  const float* xsrc0 = xg + (size_t)(bm + (t >> 3)) * 512 + (t & 7) * 2;
  const int wdst = t * 16;
  const int xdst = WTILE + (t >> 3) * 32 + (t & 7) * 4;
  // fragment offsets: A: x[row wm*32+l31][k h*8..+8]; B nr: W[col wn*128+nr*32+l31][k h*8..+8]
  const int aoff = WTILE + wm * 1024 + l31 * 32 + h * 16;
  const int boff = (wn * 128 + l31) * 32 + h * 16;

  f32x16 acc[4];
  #pragma unroll
  for (int n = 0; n < 4; ++n)
    #pragma unroll
    for (int j = 0; j < 16; ++j) acc[n][j] = 0.f;

  // ---- prologue: stage tiles 0 -> P0, 1 -> P1 ----
  {
    float2 xv0 = *(const float2*)(xsrc0);
    gload_lds16(wsrc0, P0 + wdst);
    gload_lds16(wsrc0 + 131072, P0 + 8192 + wdst);
    unsigned int p0 = (unsigned int)f2bf(xv0.x) | ((unsigned int)f2bf(xv0.y) << 16);
    *(unsigned int*)(P0 + xdst) = p0;
    float2 xv1 = *(const float2*)(xsrc0 + 16);
    gload_lds16(wsrc0 + 16, P1 + wdst);
    gload_lds16(wsrc0 + 16 + 131072, P1 + 8192 + wdst);
    unsigned int p1 = (unsigned int)f2bf(xv1.x) | ((unsigned int)f2bf(xv1.y) << 16);
    *(unsigned int*)(P1 + xdst) = p1;
    asm volatile("s_waitcnt vmcnt(0) lgkmcnt(0)" ::: "memory");
    __builtin_amdgcn_s_barrier();
  }

  auto body = [&](int kt, char* cur, char* nxt, bool drain) {
    short8 af  = *(const short8*)(cur + aoff);
    short8 bf0 = *(const short8*)(cur + boff);
    short8 bf1 = *(const short8*)(cur + boff + 1024);
    short8 bf2 = *(const short8*)(cur + boff + 2048);
    short8 bf3 = *(const short8*)(cur + boff + 3072);
    float2 xv;
    if (nxt) {
      // issue next-next tile loads; completion is only required one full
      // iteration from now (the cvt below implicitly waits vmcnt(2), which
      // forces tile t+1 -- issued last iteration -- complete before barrier)
      xv = *(const float2*)(xsrc0 + (kt + 2) * 16);
      gload_lds16(wsrc0 + (kt + 2) * 16, nxt + wdst);
      gload_lds16(wsrc0 + (kt + 2) * 16 + 131072, nxt + 8192 + wdst);
    }
    __builtin_amdgcn_s_setprio(1);
    acc[0] = __builtin_amdgcn_mfma_f32_32x32x16_bf16(af, bf0, acc[0], 0, 0, 0);
    acc[1] = __builtin_amdgcn_mfma_f32_32x32x16_bf16(af, bf1, acc[1], 0, 0, 0);
    acc[2] = __builtin_amdgcn_mfma_f32_32x32x16_bf16(af, bf2, acc[2], 0, 0, 0);
    acc[3] = __builtin_amdgcn_mfma_f32_32x32x16_bf16(af, bf3, acc[3], 0, 0, 0);
    __builtin_amdgcn_s_setprio(0);
    if (nxt) {
      unsigned int p = (unsigned int)f2bf(xv.x) | ((unsigned int)f2bf(xv.y) << 16);
      *(unsigned int*)(nxt + xdst) = p;
    }
    if (drain)
      asm volatile("s_waitcnt vmcnt(0) lgkmcnt(0)" ::: "memory");
    else
      asm volatile("s_waitcnt lgkmcnt(0)" ::: "memory");
    __builtin_amdgcn_s_barrier();
  };

  for (int kt = 0; kt < 30; kt += 3) {
    body(kt,     P0, P2, false);
    body(kt + 1, P1, P0, false);
    body(kt + 2, P2, P1, false);
  }
  body(30, P0, nullptr, true);    // drain W(31) before last consume
  body(31, P1, nullptr, false);

  // ---------------- epilogue ----------------
  // acc[nr][reg] = y[bm + wm*32 + (reg&3)+8*(reg>>2)+4*h][wn*128 + nr*32 + l31]
  const float esc = __expf(sg[0]);
  float bv[4];
  #pragma unroll
  for (int nr = 0; nr < 4; ++nr) bv[nr] = bg[wn * 128 + nr * 32 + l31];
  #pragma unroll
  for (int nr = 0; nr < 4; ++nr)
    #pragma unroll
    for (int j = 0; j < 16; ++j)
      acc[nr][j] += bv[nr];

  const bool c0 = (wn == 0) && (l31 == 0);   // this lane's nr==0 col is global col 0
  float ss[16];
  #pragma unroll
  for (int j = 0; j < 16; ++j) {
    float s = 0.f;
    #pragma unroll
    for (int nr = 0; nr < 4; ++nr) { const float v = acc[nr][j]; s += v * v; }
    if (c0) { const float v = acc[0][j]; s -= v * v; }   // exclude y0
    ss[j] = s;
  }
  // reduce over the 32 cols held within each lane-half
  #pragma unroll
  for (int m = 1; m < 32; m <<= 1)
    #pragma unroll
    for (int j = 0; j < 16; ++j)
      ss[j] += __shfl_xor(ss[j], m, 64);

  float* red = (float*)smem;           // 64 floats (phase0 region, dead)
  float* tsh = (float*)(smem + 256);   // 64 floats
  if (t < 64) red[t] = 0.f;
  __syncthreads();
  if (l31 == 0) {      // lanes 0 and 32: one add per row per wn-wave
    #pragma unroll
    for (int j = 0; j < 16; ++j) {
      const int r = wm * 32 + (j & 3) + 8 * (j >> 2) + 4 * h;
      atomicAdd(&red[r], ss[j]);
    }
  }
  if (c0) {
    #pragma unroll
    for (int j = 0; j < 16; ++j) {
      const int r = wm * 32 + (j & 3) + 8 * (j >> 2) + 4 * h;
      const float y0 = acc[0][j];
      tsh[r] = esc / (1.f + __expf(-y0)) + 1.1f;
    }
  }
  __syncthreads();

  #pragma unroll
  for (int g = 0; g < 4; ++g) {
    const int rbase = wm * 32 + 8 * g + 4 * h;
    const float4 r4 = *(const float4*)(red + rbase);
    const float4 t4 = *(const float4*)(tsh + rbase);
    #pragma unroll
    for (int j = 0; j < 4; ++j) {
      float denom = (&r4.x)[j];
      denom = denom < 1e-8f ? 1e-8f : denom;
      const float tt = (&t4.x)[j];
      const float coef = sqrtf((tt * tt - 1.f) / denom);
      float* orow = out + (size_t)(bm + rbase + j) * 512;
      #pragma unroll
      for (int nr = 0; nr < 4; ++nr) {
        const int c = wn * 128 + nr * 32 + l31;
        orow[c] = (c == 0) ? tt : acc[nr][4 * g + j] * coef;
      }
    }
  }
}

extern "C" void kernel_launch(void* const* d_in, const int* in_sizes, int n_in,
                              void* d_out, int out_size, void* d_ws, size_t ws_size,
                              hipStream_t stream) {
  const float* x = (const float*)d_in[0];
  const float* W = (const float*)d_in[1];
  const float* b = (const float*)d_in[2];
  const float* sc = (const float*)d_in[3];
  float* outp = (float*)d_out;
  unsigned short* wb = (unsigned short*)d_ws;   // 512*512*2 = 512KB scratch

  wconv_kernel<<<256, 256, 0, stream>>>(W, wb);
  lorentz_kernel<<<65536 / BM, THREADS, 0, stream>>>(x, wb, b, sc, outp);
}